// Round 2
// baseline (1111.717 us; speedup 1.0000x reference)
//
#include <hip/hip_runtime.h>
#include <math.h>

#define L_DIM 128
#define E_DIM 768
#define BK 32
#define NCHUNK (E_DIM / BK)   // 24

typedef short s16x8 __attribute__((ext_vector_type(8)));
typedef float f32x16 __attribute__((ext_vector_type(16)));

// RNE fp32 -> bf16 (bits in low 16). No NaN handling needed (finite data).
__device__ __forceinline__ unsigned bf16_rne_bits(float v) {
    unsigned u = __float_as_uint(v);
    return (u + 0x7FFFu + ((u >> 16) & 1u)) >> 16;
}

// One block per (b,k) pair (B*K = 1024 blocks), 256 threads = 4 waves.
// Per chunk of 32 k-values:
//   Phase A: each thread owns one row (ctx for t<128, ent for t>=128); converts
//     its 32 fp32 to (hi,lo) bf16 pairs, accumulates |row|^2 and w0-dots in fp32
//     from registers, stages hi/lo to LDS [row][k] with slot^(row&7) XOR swizzle.
//   Phase B: split-bf16 MFMA GEMM: dot = Ch*Eh^T + Ch*El^T + Cl*Eh^T  (lo*lo
//     dropped, ~2^-18 relative) via mfma_f32_32x32x16_bf16; wave w owns output
//     rows 32w..32w+31 (4 col tiles, 4x f32x16 acc). Normalized-sim error ~2e-7,
//     same order as fp32-FMA accumulation-order noise in the prior kernel.
//   Correctness note: A and B frags use the same (lanegroup,elem)->k assignment;
//     32x32 MFMA A/B layouts are symmetric (row=l%32 / col=l%32), so any
//     consistent k-permutation of both operands leaves C.E^T unchanged — the
//     kernel does not depend on the exact operand k-layout, only on the
//     HW-measured C/D layout (col=lane&31, row=(reg&3)+8(reg>>2)+4(lane>>5)).
// Epilogue: argmax_m dot(c_l,e_m)*inv_en[m] straight from MFMA C-layout via
//   shfl_xor value+index reduce, then the tiny MLP chain + block sum (unchanged).
__global__ __launch_bounds__(256, 3) void som_mlp_kernel(
    const float* __restrict__ ctx,
    const float* __restrict__ w0, const float* __restrict__ b0,
    const float* __restrict__ w1, const float* __restrict__ b1,
    const float* __restrict__ w2, const float* __restrict__ b2,
    const float* __restrict__ w3, const float* __restrict__ b3,
    const float* __restrict__ w4, const float* __restrict__ b4,
    const float* __restrict__ w5, const float* __restrict__ b5,
    const float* __restrict__ w6, const float* __restrict__ b6,
    float* __restrict__ out)
{
    // [row][64] ushorts; slots of 8 ushorts (16B). Logical slots 0-3 = hi
    // k-octets, 4-7 = lo k-octets. Physical slot = logical ^ (row & 7).
    __shared__ __align__(16) unsigned short cT[L_DIM][64];
    __shared__ __align__(16) unsigned short eT[L_DIM][64];
    __shared__ float invn[2 * L_DIM];   // [0:128] 1/|c_l|, [128:256] 1/|e_m|
    __shared__ float Af[L_DIM][5];      // ctx_n . w0[:, :768]
    __shared__ float Bf[L_DIM][5];      // ent_n . w0[:, 768:]
    __shared__ int   bidx[L_DIM];
    __shared__ float psum[2];

    const int t   = threadIdx.x;
    const int blk = blockIdx.x;
    const int mat = t >> 7;         // 0 = context, 1 = entity (wave-uniform)
    const int l   = t & 127;
    const int matu = __builtin_amdgcn_readfirstlane(mat);

    const float4* rowp = (const float4*)(ctx + ((size_t)(blk * 2 + mat) * L_DIM + l) * E_DIM);
    const float* w0h = w0 + matu * 768;          // uniform -> scalar loads
    unsigned short* myrow = (mat ? &eT[0][0] : &cT[0][0]) + l * 64;
    const int lsw = l & 7;

    // MFMA-side identities
    const int lane = t & 63;
    const int wv   = t >> 6;        // wave id 0..3 -> output rows 32*wv..
    const int cb   = lane & 31;     // row-within-strip (A) / col-within-tile (B)
    const int kg   = lane >> 5;     // k-group 0/1
    const unsigned short* arp = &cT[0][0] + (32 * wv + cb) * 64;
    const int asw = cb & 7;         // (32*wv + cb) & 7 == cb & 7 == (32*tc+cb)&7

    float nrm = 0.f;
    float dots[5] = {0.f, 0.f, 0.f, 0.f, 0.f};
    f32x16 acc[4];
    #pragma unroll
    for (int tc = 0; tc < 4; ++tc)
        #pragma unroll
        for (int i = 0; i < 16; ++i) acc[tc][i] = 0.f;

    float4 pf[8];
    #pragma unroll
    for (int q = 0; q < 8; ++q) pf[q] = rowp[q];

    #pragma unroll 1
    for (int c = 0; c < NCHUNK; ++c) {
        // ---- Phase A: convert + fp32 stats + swizzled LDS stage ----
        #pragma unroll
        for (int g = 0; g < 4; ++g) {
            float vv[8] = {pf[2*g].x, pf[2*g].y, pf[2*g].z, pf[2*g].w,
                           pf[2*g+1].x, pf[2*g+1].y, pf[2*g+1].z, pf[2*g+1].w};
            s16x8 h8, l8;
            #pragma unroll
            for (int i = 0; i < 8; ++i) {
                float v = vv[i];
                nrm = fmaf(v, v, nrm);
                unsigned hb = bf16_rne_bits(v);
                float hf = __uint_as_float(hb << 16);
                float r  = v - hf;                 // exact (nearby subtraction)
                unsigned lb = bf16_rne_bits(r);
                h8[i] = (short)hb;
                l8[i] = (short)lb;
            }
            #pragma unroll
            for (int j = 0; j < 5; ++j) {
                const float* wr = w0h + j * 1536 + c * BK + g * 8;  // uniform
                float d = dots[j];
                #pragma unroll
                for (int i = 0; i < 8; ++i) d = fmaf(vv[i], wr[i], d);
                dots[j] = d;
            }
            *(s16x8*)(myrow + ((g       ^ lsw) << 3)) = h8;
            *(s16x8*)(myrow + (((g + 4) ^ lsw) << 3)) = l8;
        }
        // prefetch next chunk (pf dead after conversion; hidden under barrier+MFMA)
        if (c + 1 < NCHUNK) {
            #pragma unroll
            for (int q = 0; q < 8; ++q) pf[q] = rowp[(c + 1) * 8 + q];
        }
        __syncthreads();

        // ---- Phase B: split-bf16 MFMA (hi*hi + hi*lo + lo*hi) ----
        #pragma unroll
        for (int k16 = 0; k16 < 2; ++k16) {
            const int sl = k16 * 2 + kg;          // logical hi slot for this frag
            s16x8 ah = *(const s16x8*)(arp + (((sl    ) ^ asw) << 3));
            s16x8 al = *(const s16x8*)(arp + (((sl + 4) ^ asw) << 3));
            #pragma unroll
            for (int tc = 0; tc < 4; ++tc) {
                const unsigned short* brp = &eT[0][0] + (32 * tc + cb) * 64;
                s16x8 bh = *(const s16x8*)(brp + (((sl    ) ^ asw) << 3));
                s16x8 bl = *(const s16x8*)(brp + (((sl + 4) ^ asw) << 3));
                acc[tc] = __builtin_amdgcn_mfma_f32_32x32x16_bf16(ah, bh, acc[tc], 0, 0, 0);
                acc[tc] = __builtin_amdgcn_mfma_f32_32x32x16_bf16(ah, bl, acc[tc], 0, 0, 0);
                acc[tc] = __builtin_amdgcn_mfma_f32_32x32x16_bf16(al, bh, acc[tc], 0, 0, 0);
            }
        }
        __syncthreads();
    }

    // ---- finalize norms + first-layer partials (fp32 path, unchanged) ----
    {
        float inv = 1.0f / sqrtf(nrm);
        invn[t] = inv;                       // t == mat*128 + l
        float* dst = mat ? &Bf[l][0] : &Af[l][0];
        #pragma unroll
        for (int j = 0; j < 5; ++j) dst[j] = dots[j] * inv;
    }
    __syncthreads();

    // ---- argmax from MFMA C-layout: col = 32*tc + cb, row = (reg&3)+8*(reg>>2)+4*kg ----
    {
        float ien4[4];
        #pragma unroll
        for (int tc = 0; tc < 4; ++tc) ien4[tc] = invn[128 + 32 * tc + cb];
        const int rbase = 32 * wv + 4 * kg;
        #pragma unroll
        for (int reg = 0; reg < 16; ++reg) {
            const int r = rbase + (reg & 3) + 8 * (reg >> 2);
            float bestv = acc[0][reg] * ien4[0];
            int   besti = cb;
            #pragma unroll
            for (int tc = 1; tc < 4; ++tc) {
                float s = acc[tc][reg] * ien4[tc];
                if (s > bestv) { bestv = s; besti = 32 * tc + cb; }  // m ascends with tc
            }
            // reduce across the 32 lanes of this half (rows disjoint across halves)
            #pragma unroll
            for (int off = 1; off < 32; off <<= 1) {
                float ov = __shfl_xor(bestv, off);
                int   oi = __shfl_xor(besti, off);
                if (ov > bestv || (ov == bestv && oi < besti)) { bestv = ov; besti = oi; }
            }
            if (cb == 0) bidx[r] = besti;
        }
    }
    __syncthreads();

    // ---- tiny MLP chain + block reduction (unchanged semantics) ----
    if (t < 128) {
        const int besti = bidx[t];
        float x0[5];
        #pragma unroll
        for (int j = 0; j < 5; ++j)
            x0[j] = tanhf(Af[t][j] + Bf[besti][j] + b0[j]);
        float y0 = b1[0], y1 = b1[1];
        #pragma unroll
        for (int j = 0; j < 5; ++j) {
            y0 = fmaf(w1[j],     x0[j], y0);
            y1 = fmaf(w1[5 + j], x0[j], y1);
        }
        y0 = tanhf(y0); y1 = tanhf(y1);
        float z = tanhf(fmaf(w2[0], y0, fmaf(w2[1], y1, b2[0])));
        z = tanhf(fmaf(w3[0], z, b3[0]));
        z = tanhf(fmaf(w4[0], z, b4[0]));
        z = tanhf(fmaf(w5[0], z, b5[0]));
        z = fmaf(w6[0], z, b6[0]);
        #pragma unroll
        for (int off = 32; off > 0; off >>= 1) z += __shfl_down(z, off);
        if ((t & 63) == 0) psum[t >> 6] = z;
    }
    __syncthreads();
    if (t == 0) out[blk] = psum[0] + psum[1];
}

extern "C" void kernel_launch(void* const* d_in, const int* in_sizes, int n_in,
                              void* d_out, int out_size, void* d_ws, size_t ws_size,
                              hipStream_t stream) {
    (void)in_sizes; (void)n_in; (void)d_ws; (void)ws_size; (void)out_size;
    const float* ctx = (const float*)d_in[0];
    som_mlp_kernel<<<dim3(1024), dim3(256), 0, stream>>>(
        ctx,
        (const float*)d_in[1],  (const float*)d_in[2],
        (const float*)d_in[3],  (const float*)d_in[4],
        (const float*)d_in[5],  (const float*)d_in[6],
        (const float*)d_in[7],  (const float*)d_in[8],
        (const float*)d_in[9],  (const float*)d_in[10],
        (const float*)d_in[11], (const float*)d_in[12],
        (const float*)d_in[13], (const float*)d_in[14],
        (float*)d_out);
}